// Round 2
// baseline (314.255 us; speedup 1.0000x reference)
//
#include <hip/hip_runtime.h>
#include <hip/hip_bf16.h>

#define K_DIM 64

typedef __attribute__((ext_vector_type(8))) __bf16 bf16x8;
typedef __attribute__((ext_vector_type(8))) unsigned short u16x8;
typedef __attribute__((ext_vector_type(4))) float  f32x4;

// Load one row of P (fp32, 64 elems), compute 1/max(||row||,eps) via
// 4-lane-group reduce, and emit the two bf16x8 MFMA fragments this lane
// owns (k = half*32 + quad*8 + j). Numerics identical to the old separate
// normalize kernel: fp32 norm, fp32 scale, __float2bfloat16 (RNE) per elem.
__device__ inline void norm_frags(const f32x4* __restrict__ P, int row,
                                  int quad, bf16x8* f0, bf16x8* f1)
{
    size_t base = (size_t)row * 16 + quad * 2;   // row = 16 float4s
    f32x4 a = P[base];
    f32x4 b = P[base + 1];
    f32x4 c = P[base + 8];
    f32x4 d = P[base + 9];
    float s = 0.f;
    #pragma unroll
    for (int i = 0; i < 4; ++i)
        s += a[i]*a[i] + b[i]*b[i] + c[i]*c[i] + d[i]*d[i];
    // full row lives in lanes {l16, l16+16, l16+32, l16+48}
    s += __shfl_xor(s, 16, 64);
    s += __shfl_xor(s, 32, 64);
    float inv = 1.0f / fmaxf(sqrtf(s), 1e-8f);
    u16x8 r0, r1;
    #pragma unroll
    for (int i = 0; i < 4; ++i) {
        r0[i]   = __builtin_bit_cast(unsigned short, __float2bfloat16(a[i] * inv));
        r0[i+4] = __builtin_bit_cast(unsigned short, __float2bfloat16(b[i] * inv));
        r1[i]   = __builtin_bit_cast(unsigned short, __float2bfloat16(c[i] * inv));
        r1[i+4] = __builtin_bit_cast(unsigned short, __float2bfloat16(d[i] * inv));
    }
    *f0 = __builtin_bit_cast(bf16x8, r0);
    *f1 = __builtin_bit_cast(bf16x8, r1);
}

// Single fused kernel: normalize-on-the-fly + bf16 MFMA + streaming C write.
//
// Block = 128x128 tile, 4 waves; wave w owns rows [w*32, w*32+32) x 128 cols.
// All global loads (fp32 A/B rows -> normalized bf16 fragments in registers)
// complete before any store; the C drain is fire-and-forget.
//
// Grid is 1-D with n as the fast axis + bijective XCD-chunk remap: each XCD
// owns 512 consecutive tiles = 8 full row-bands = one contiguous 32 MB slab
// of C swept in address order, with all of B (2 MB fp32) L2-resident per XCD.
//
// C stores are non-temporal: C is write-once/never-read; keep A/B in L2.
__global__ __launch_bounds__(256) void cosine_fused_kernel(
    const f32x4* __restrict__ A, const f32x4* __restrict__ B,
    float* __restrict__ C, int N, int gx)
{
    __shared__ __align__(16) float smem[4][16][132];   // 33.8 KB, per-wave slabs

    const int lane = threadIdx.x & 63;
    const int wave = threadIdx.x >> 6;
    const int l16  = lane & 15;
    const int quad = lane >> 4;

    int flat = blockIdx.x;
    int nblk = gridDim.x;
    int newf = flat;
    if ((nblk & 7) == 0) {                  // bijective XCD chunking
        int chunk = nblk >> 3;
        newf = (flat & 7) * chunk + (flat >> 3);
    }
    const int bn = newf % gx;               // n fast -> sequential C sweep
    const int bm = newf / gx;

    const int gm0 = bm * 128 + wave * 32;
    const int gn0 = bn * 128;

    // Normalized B fragments for all 8 n-tiles (each wave keeps its own copy;
    // redundant L2 reads are cheaper than a cross-wave LDS handoff + barrier).
    bf16x8 bfrag[8][2];
    #pragma unroll
    for (int tn = 0; tn < 8; ++tn)
        norm_frags(B, gn0 + tn * 16 + l16, quad, &bfrag[tn][0], &bfrag[tn][1]);

    // Normalized A fragments for this wave's two m-tiles.
    bf16x8 afrag[2][2];
    #pragma unroll
    for (int tm = 0; tm < 2; ++tm)
        norm_frags(A, gm0 + tm * 16 + l16, quad, &afrag[tm][0], &afrag[tm][1]);

    float (*buf)[132] = smem[wave];

    #pragma unroll
    for (int tm = 0; tm < 2; ++tm) {
        // Compute + stage one 16x128 slab. C/D layout (m89/m91): col = l16,
        // row = quad*4 + r. Staging is <=2-way bank-aliased (free, m136).
        #pragma unroll
        for (int tn = 0; tn < 8; ++tn) {
            f32x4 a = {0.f, 0.f, 0.f, 0.f};
            a = __builtin_amdgcn_mfma_f32_16x16x32_bf16(afrag[tm][0], bfrag[tn][0], a, 0, 0, 0);
            a = __builtin_amdgcn_mfma_f32_16x16x32_bf16(afrag[tm][1], bfrag[tn][1], a, 0, 0, 0);
            #pragma unroll
            for (int r = 0; r < 4; ++r)
                buf[quad * 4 + r][tn * 16 + l16] = a[r];
        }

        // Drain: 8 nt-store insts per slab; each inst = 2 rows x 512 B
        // contiguous, rows ascending. Per-wave buffer + in-order same-wave
        // DS pipe => no __syncthreads anywhere in the kernel.
        #pragma unroll
        for (int i = 0; i < 8; ++i) {
            int rr = i * 2 + (lane >> 5);
            int cc = (lane & 31) * 4;
            f32x4 v = *(const f32x4*)&buf[rr][cc];
            __builtin_nontemporal_store(
                v, (f32x4*)&C[(size_t)(gm0 + tm * 16 + rr) * N + gn0 + cc]);
        }
    }
}

extern "C" void kernel_launch(void* const* d_in, const int* in_sizes, int n_in,
                              void* d_out, int out_size, void* d_ws, size_t ws_size,
                              hipStream_t stream) {
    const float* A = (const float*)d_in[0];
    const float* B = (const float*)d_in[1];
    int nA = in_sizes[0] / K_DIM;   // 8192
    int nB = in_sizes[1] / K_DIM;   // 8192
    float* C = (float*)d_out;

    int gx = nB / 128;              // col tiles (fast axis)
    int gy = nA / 128;              // row tiles
    cosine_fused_kernel<<<dim3(gx * gy), dim3(256), 0, stream>>>(
        (const f32x4*)A, (const f32x4*)B, C, nB, gx);
}

// Round 5
// 288.276 us; speedup vs baseline: 1.0901x; 1.0901x over previous
//
#include <hip/hip_runtime.h>
#include <hip/hip_bf16.h>

#define K_DIM 64

typedef __attribute__((ext_vector_type(8))) __bf16 bf16x8;
typedef __attribute__((ext_vector_type(4))) float  f32x4;

// Kernel 1: row-normalize A and B (fp32) -> bf16 rows in workspace.
// One wave per row: 64 lanes == 64 elements. (Round-0 verified numerics.)
__global__ __launch_bounds__(256) void normalize_bf16_kernel(
    const float* __restrict__ A, const float* __restrict__ B,
    __hip_bfloat16* __restrict__ An, __hip_bfloat16* __restrict__ Bn,
    int nA, int nB)
{
    int row  = blockIdx.x * 4 + (threadIdx.x >> 6);
    int lane = threadIdx.x & 63;
    if (row >= nA + nB) return;
    const float*      src = (row < nA) ? A  : B;
    __hip_bfloat16*   dst = (row < nA) ? An : Bn;
    int r = (row < nA) ? row : row - nA;

    float v = src[(size_t)r * K_DIM + lane];
    float s = v * v;
    #pragma unroll
    for (int off = 32; off >= 1; off >>= 1)
        s += __shfl_xor(s, off, 64);
    float inv = 1.0f / fmaxf(sqrtf(s), 1e-8f);   // matches max(||a||, eps)
    dst[(size_t)r * K_DIM + lane] = __float2bfloat16(v * inv);
}

// Kernel 2: C = An * Bn^T via bf16 MFMA — write-locality-targeted layout,
// expressed with per-wave LDS slabs and ZERO barriers (round-0/1 proven
// structure).
//
// Block = 64 rows x 256 cols, 4 waves. Wave w owns rows [w*16, w*16+16)
// across all 256 cols: 1 m-tile x 16 n-tiles of 16x16, K=64 -> 32 MFMA.
//
// Drain: wave stages all 16 n-tiles into its private 16x260 slab, then emits
// 16 store insts, each ONE FULL 1 KB contiguous C row-segment (64 lanes x
// 16 B), rows ascending. Combined with the n-fast + bijective-XCD-chunk grid
// map, each XCD sweeps a contiguous 32 MB horizontal band of C in address
// order (fill-like), with B L2-resident per XCD.
//
// All global loads (A/B fragments -> registers) are issued before any store.
__global__ __launch_bounds__(256) void cosine_gemm_kernel(
    const f32x4* __restrict__ An, const f32x4* __restrict__ Bn,
    float* __restrict__ C, int N, int gxn)
{
    // Per-wave slab: 16 rows x 260 floats. Stride 260 => staging writes are
    // <=2-way bank-aliased (free, m136): quad contributes banks {0,16,0,16}.
    // Row stride 1040 B stays 16 B aligned for the f32x4 drain reads.
    __shared__ __align__(16) float smem[4][16][260];   // 66.6 KB total

    const int lane = threadIdx.x & 63;
    const int wave = threadIdx.x >> 6;
    const int l16  = lane & 15;
    const int quad = lane >> 4;

    // Bijective XCD chunking (nblk % 8 == 0 here): XCD x owns nblk/8
    // consecutive logical tiles; n is the fast logical axis.
    int flat = blockIdx.x;
    int nblk = gridDim.x;
    int newf = flat;
    if ((nblk & 7) == 0) {
        int chunk = nblk >> 3;
        newf = (flat & 7) * chunk + (flat >> 3);
    }
    const int bn = newf % gxn;
    const int bm = newf / gxn;

    const int gm0 = bm * 64 + wave * 16;     // this wave's 16 C rows
    const int gnb = bn * 256;                // block col base

    // B fragments for all 16 n-tiles:
    // B[n = gnb+tn*16+l16][k = half*32+quad*8+j]; bf16 row = 8 f32x4.
    bf16x8 bfrag[16][2];
    #pragma unroll
    for (int tn = 0; tn < 16; ++tn) {
        size_t rb = (size_t)(gnb + tn * 16 + l16) * 8;
        bfrag[tn][0] = __builtin_bit_cast(bf16x8, Bn[rb + quad]);
        bfrag[tn][1] = __builtin_bit_cast(bf16x8, Bn[rb + 4 + quad]);
    }
    // A fragments for this wave's single m-tile.
    size_t ra = (size_t)(gm0 + l16) * 8;
    bf16x8 a0 = __builtin_bit_cast(bf16x8, An[ra + quad]);
    bf16x8 a1 = __builtin_bit_cast(bf16x8, An[ra + 4 + quad]);

    float (*buf)[260] = smem[wave];

    // Compute + stage the 16x256 slab. C/D layout (m89/m91): col = l16,
    // row = quad*4 + r.
    #pragma unroll
    for (int tn = 0; tn < 16; ++tn) {
        f32x4 a = {0.f, 0.f, 0.f, 0.f};
        a = __builtin_amdgcn_mfma_f32_16x16x32_bf16(a0, bfrag[tn][0], a, 0, 0, 0);
        a = __builtin_amdgcn_mfma_f32_16x16x32_bf16(a1, bfrag[tn][1], a, 0, 0, 0);
        #pragma unroll
        for (int r = 0; r < 4; ++r)
            buf[quad * 4 + r][tn * 16 + l16] = a[r];
    }

    // Drain: 16 store insts; each = one full 1 KB contiguous C row-segment
    // (64 lanes x 16 B), rows ascending. Per-wave buffer + in-order same-wave
    // DS pipe => no __syncthreads anywhere in the kernel.
    #pragma unroll
    for (int rr = 0; rr < 16; ++rr) {
        f32x4 v = *(const f32x4*)&buf[rr][lane * 4];
        *(f32x4*)&C[(size_t)(gm0 + rr) * N + gnb + lane * 4] = v;
    }
}

extern "C" void kernel_launch(void* const* d_in, const int* in_sizes, int n_in,
                              void* d_out, int out_size, void* d_ws, size_t ws_size,
                              hipStream_t stream) {
    const float* A = (const float*)d_in[0];
    const float* B = (const float*)d_in[1];
    int nA = in_sizes[0] / K_DIM;   // 8192
    int nB = in_sizes[1] / K_DIM;   // 8192
    float* C = (float*)d_out;

    __hip_bfloat16* An = (__hip_bfloat16*)d_ws;
    __hip_bfloat16* Bn = An + (size_t)nA * K_DIM;   // 2 MB total in d_ws

    int totalRows = nA + nB;
    normalize_bf16_kernel<<<dim3((totalRows + 3) / 4), dim3(256), 0, stream>>>(
        A, B, An, Bn, nA, nB);

    int gxm = nA / 64;              // 128 row-tile bands
    int gxn = nB / 256;             // 32 col tiles (fast logical axis)
    cosine_gemm_kernel<<<dim3(gxm * gxn), dim3(256), 0, stream>>>(
        (const f32x4*)An, (const f32x4*)Bn, C, nB, gxn);
}

// Round 6
// 264.297 us; speedup vs baseline: 1.1890x; 1.0907x over previous
//
#include <hip/hip_runtime.h>
#include <hip/hip_bf16.h>

#define K_DIM 64

typedef __attribute__((ext_vector_type(8))) __bf16 bf16x8;
typedef __attribute__((ext_vector_type(4))) float  f32x4;

// Kernel 1: row-normalize A and B (fp32) -> bf16 rows in workspace.
// One wave per row: 64 lanes == 64 elements. (Round-0 verified numerics.)
__global__ __launch_bounds__(256) void normalize_bf16_kernel(
    const float* __restrict__ A, const float* __restrict__ B,
    __hip_bfloat16* __restrict__ An, __hip_bfloat16* __restrict__ Bn,
    int nA, int nB)
{
    int row  = blockIdx.x * 4 + (threadIdx.x >> 6);
    int lane = threadIdx.x & 63;
    if (row >= nA + nB) return;
    const float*      src = (row < nA) ? A  : B;
    __hip_bfloat16*   dst = (row < nA) ? An : Bn;
    int r = (row < nA) ? row : row - nA;

    float v = src[(size_t)r * K_DIM + lane];
    float s = v * v;
    #pragma unroll
    for (int off = 32; off >= 1; off >>= 1)
        s += __shfl_xor(s, off, 64);
    float inv = 1.0f / fmaxf(sqrtf(s), 1e-8f);   // matches max(||a||, eps)
    dst[(size_t)r * K_DIM + lane] = __float2bfloat16(v * inv);
}

// Kernel 2: C = An * Bn^T via bf16 MFMA — persistent strip-walker.
//
// Grid = 512 blocks (2 per CU, co-resident). Block = (strip, band):
// strip = bid>>3 -> cols [strip*128, strip*128+128); band = bid&7 -> rows
// [band*1024, band*1024+1024). Under round-robin dispatch bid&7 == XCD, so
// each XCD writes one contiguous 32 MB horizontal band of C.
//
// Block loads its B fragments ONCE (8 n-tiles/wave), then walks 8 m-tiles
// of 128 rows. Wave w owns rows [w*32, w*32+32) of each m-tile. Per tile:
// double-buffered A prefetch (issued BEFORE the stores, so the MFMA's vmcnt
// wait for A never drains the store queue) -> 32 MFMA -> per-wave LDS
// transpose -> 16 stores of 2 rows x 512 B, rows ascending. Store issue is
// near-continuous in steady state — the fill-like regime the counters show
// sustains 6.5 TB/s.
//
// No __syncthreads anywhere: per-wave slabs + in-order same-wave DS pipe.
__global__ __launch_bounds__(256) void cosine_gemm_kernel(
    const f32x4* __restrict__ An, const f32x4* __restrict__ Bn,
    float* __restrict__ C, int N)
{
    // Per-wave slab: 16 rows x 132 floats. Staging writes <=2-way bank
    // aliased (free, m136); rows 16 B aligned for the b128 drain reads.
    __shared__ __align__(16) float smem[4][16][132];   // 33.8 KB

    const int lane = threadIdx.x & 63;
    const int wave = threadIdx.x >> 6;
    const int l16  = lane & 15;
    const int quad = lane >> 4;

    const int band  = blockIdx.x & 7;
    const int strip = blockIdx.x >> 3;
    const int gn0   = strip * 128;
    const int rw0   = band * 1024 + wave * 32;   // wave's first row

    // B fragments for the strip's 8 n-tiles, loaded once:
    // B[n = gn0+tn*16+l16][k = half*32+quad*8+j]; bf16 row = 8 f32x4.
    bf16x8 bfrag[8][2];
    #pragma unroll
    for (int tn = 0; tn < 8; ++tn) {
        size_t rb = (size_t)(gn0 + tn * 16 + l16) * 8;
        bfrag[tn][0] = __builtin_bit_cast(bf16x8, Bn[rb + quad]);
        bfrag[tn][1] = __builtin_bit_cast(bf16x8, Bn[rb + 4 + quad]);
    }

    float (*buf)[132] = smem[wave];

    // Double-buffered A fragments: [parity][m-subtile][k-half].
    // t-loop is fully unrolled -> all indices compile-time (no scratch).
    bf16x8 af[2][2][2];
    #pragma unroll
    for (int tm = 0; tm < 2; ++tm) {
        size_t ra = (size_t)(rw0 + tm * 16 + l16) * 8;
        af[0][tm][0] = __builtin_bit_cast(bf16x8, An[ra + quad]);
        af[0][tm][1] = __builtin_bit_cast(bf16x8, An[ra + 4 + quad]);
    }

    #pragma unroll
    for (int t = 0; t < 8; ++t) {
        const int cur = t & 1, nxt = cur ^ 1;
        // Prefetch next m-tile's A BEFORE this tile's stores are issued.
        if (t < 7) {
            #pragma unroll
            for (int tm = 0; tm < 2; ++tm) {
                size_t ra = (size_t)(rw0 + (t + 1) * 128 + tm * 16 + l16) * 8;
                af[nxt][tm][0] = __builtin_bit_cast(bf16x8, An[ra + quad]);
                af[nxt][tm][1] = __builtin_bit_cast(bf16x8, An[ra + 4 + quad]);
            }
        }
        const int gm0 = rw0 + t * 128;

        #pragma unroll
        for (int tm = 0; tm < 2; ++tm) {
            // Compute + stage one 16x128 slab. C/D layout (m89/m91):
            // col = l16, row = quad*4 + r.
            #pragma unroll
            for (int tn = 0; tn < 8; ++tn) {
                f32x4 a = {0.f, 0.f, 0.f, 0.f};
                a = __builtin_amdgcn_mfma_f32_16x16x32_bf16(af[cur][tm][0], bfrag[tn][0], a, 0, 0, 0);
                a = __builtin_amdgcn_mfma_f32_16x16x32_bf16(af[cur][tm][1], bfrag[tn][1], a, 0, 0, 0);
                #pragma unroll
                for (int r = 0; r < 4; ++r)
                    buf[quad * 4 + r][tn * 16 + l16] = a[r];
            }
            // Drain: 8 store insts; each = 2 rows x 512 B contiguous
            // (lanes 0-31 -> row 2i, lanes 32-63 -> row 2i+1), ascending.
            #pragma unroll
            for (int i = 0; i < 8; ++i) {
                int rr = i * 2 + (lane >> 5);
                int cc = (lane & 31) * 4;
                f32x4 v = *(const f32x4*)&buf[rr][cc];
                *(f32x4*)&C[(size_t)(gm0 + tm * 16 + rr) * N + gn0 + cc] = v;
            }
        }
    }
}

extern "C" void kernel_launch(void* const* d_in, const int* in_sizes, int n_in,
                              void* d_out, int out_size, void* d_ws, size_t ws_size,
                              hipStream_t stream) {
    const float* A = (const float*)d_in[0];
    const float* B = (const float*)d_in[1];
    int nA = in_sizes[0] / K_DIM;   // 8192
    int nB = in_sizes[1] / K_DIM;   // 8192
    float* C = (float*)d_out;

    __hip_bfloat16* An = (__hip_bfloat16*)d_ws;
    __hip_bfloat16* Bn = An + (size_t)nA * K_DIM;   // 2 MB total in d_ws

    int totalRows = nA + nB;
    normalize_bf16_kernel<<<dim3((totalRows + 3) / 4), dim3(256), 0, stream>>>(
        A, B, An, Bn, nA, nB);

    // 64 col-strips x 8 row-bands = 512 persistent blocks (2 per CU).
    cosine_gemm_kernel<<<dim3(512), dim3(256), 0, stream>>>(
        (const f32x4*)An, (const f32x4*)Bn, C, nB);
}

// Round 7
// 262.788 us; speedup vs baseline: 1.1959x; 1.0057x over previous
//
#include <hip/hip_runtime.h>
#include <hip/hip_bf16.h>

#define K_DIM 64

typedef __attribute__((ext_vector_type(8)))  __bf16 bf16x8;
typedef __attribute__((ext_vector_type(4)))  float  f32x4;
typedef __attribute__((ext_vector_type(16))) float  f32x16;

// Kernel 1: row-normalize A and B (fp32) -> bf16 rows in workspace.
// One wave per row: 64 lanes == 64 elements. (Round-0 verified numerics.)
__global__ __launch_bounds__(256) void normalize_bf16_kernel(
    const float* __restrict__ A, const float* __restrict__ B,
    __hip_bfloat16* __restrict__ An, __hip_bfloat16* __restrict__ Bn,
    int nA, int nB)
{
    int row  = blockIdx.x * 4 + (threadIdx.x >> 6);
    int lane = threadIdx.x & 63;
    if (row >= nA + nB) return;
    const float*      src = (row < nA) ? A  : B;
    __hip_bfloat16*   dst = (row < nA) ? An : Bn;
    int r = (row < nA) ? row : row - nA;

    float v = src[(size_t)r * K_DIM + lane];
    float s = v * v;
    #pragma unroll
    for (int off = 32; off >= 1; off >>= 1)
        s += __shfl_xor(s, off, 64);
    float inv = 1.0f / fmaxf(sqrtf(s), 1e-8f);   // matches max(||a||, eps)
    dst[(size_t)r * K_DIM + lane] = __float2bfloat16(v * inv);
}

// Kernel 2: C = An * Bn^T via 32x32x16 bf16 MFMA — ZERO-LDS epilogue.
//
// Every prior variant drained C through an LDS round-trip (ds_write ->
// lgkmcnt -> ds_read_b128 -> store); that chain is the one invariant across
// all measured structures. This version stores straight from accumulators.
//
// 32x32x16 C/D layout (m74/m101, HW-verified): col = lane&31,
// row = (reg&3) + 8*(reg>>2) + 4*(lane>>5). So ONE global_store_dword of a
// single acc reg writes 2 rows x 128 B = two full aligned cachelines.
// Rows ascend with reg index ((reg&3)+8*(reg>>2) is monotone in reg).
//
// Block = 128x128 tile, 4 waves, wave = 2x2 of 32x32 tiles (16 MFMA, K=64).
// No LDS, no barriers; all loads precede all stores. Grid identical to the
// best-measured round-0 kernel.
__global__ __launch_bounds__(256) void cosine_gemm_kernel(
    const f32x4* __restrict__ An, const f32x4* __restrict__ Bn,
    float* __restrict__ C, int N)
{
    const int lane = threadIdx.x & 63;
    const int wave = threadIdx.x >> 6;
    const int l32  = lane & 31;
    const int half = lane >> 5;            // 0..1
    const int wm   = wave >> 1;            // 0..1
    const int wn   = wave & 1;             // 0..1
    const int gm0  = blockIdx.x * 128 + wm * 64;
    const int gn0  = blockIdx.y * 128 + wn * 64;

    // Input fragments for 32x32x16: lane holds row (l32), elems
    // k = c*16 + half*8 + j  (j=0..7). Row = 64 bf16 = 8 f32x4;
    // f32x4 index = c*2 + half.
    bf16x8 afrag[2][4], bfrag[2][4];
    #pragma unroll
    for (int t = 0; t < 2; ++t) {
        size_t ra = (size_t)(gm0 + t * 32 + l32) * 8;
        size_t rb = (size_t)(gn0 + t * 32 + l32) * 8;
        #pragma unroll
        for (int c = 0; c < 4; ++c) {
            afrag[t][c] = __builtin_bit_cast(bf16x8, An[ra + c * 2 + half]);
            bfrag[t][c] = __builtin_bit_cast(bf16x8, Bn[rb + c * 2 + half]);
        }
    }

    f32x16 acc[2][2];
    #pragma unroll
    for (int tm = 0; tm < 2; ++tm)
        #pragma unroll
        for (int tn = 0; tn < 2; ++tn) {
            f32x16 a = {};
            #pragma unroll
            for (int c = 0; c < 4; ++c)
                a = __builtin_amdgcn_mfma_f32_32x32x16_bf16(
                        afrag[tm][c], bfrag[tn][c], a, 0, 0, 0);
            acc[tm][tn] = a;
        }

    // Direct store: rows ascending; per (tm,r) the two tn insts cover
    // 2 rows x 256 B of the wave's 64-col span (4 full cachelines).
    #pragma unroll
    for (int tm = 0; tm < 2; ++tm)
        #pragma unroll
        for (int r = 0; r < 16; ++r) {
            int row = gm0 + tm * 32 + (r & 3) + 8 * (r >> 2) + 4 * half;
            #pragma unroll
            for (int tn = 0; tn < 2; ++tn)
                C[(size_t)row * N + gn0 + tn * 32 + l32] = acc[tm][tn][r];
        }
}

extern "C" void kernel_launch(void* const* d_in, const int* in_sizes, int n_in,
                              void* d_out, int out_size, void* d_ws, size_t ws_size,
                              hipStream_t stream) {
    const float* A = (const float*)d_in[0];
    const float* B = (const float*)d_in[1];
    int nA = in_sizes[0] / K_DIM;   // 8192
    int nB = in_sizes[1] / K_DIM;   // 8192
    float* C = (float*)d_out;

    __hip_bfloat16* An = (__hip_bfloat16*)d_ws;
    __hip_bfloat16* Bn = An + (size_t)nA * K_DIM;   // 2 MB total in d_ws

    int totalRows = nA + nB;
    normalize_bf16_kernel<<<dim3((totalRows + 3) / 4), dim3(256), 0, stream>>>(
        A, B, An, Bn, nA, nB);

    dim3 grid(nA / 128, nB / 128);
    cosine_gemm_kernel<<<grid, dim3(256), 0, stream>>>(
        (const f32x4*)An, (const f32x4*)Bn, C, nB);
}